// Round 5
// baseline (1199.179 us; speedup 1.0000x reference)
//
#include <hip/hip_runtime.h>
#include <stdint.h>

typedef _Float16 f16;
typedef _Float16 f16x8 __attribute__((ext_vector_type(8)));
typedef float f32x4 __attribute__((ext_vector_type(4)));

#define B_ROWS 32768
#define DIM 512
#define NP 8
#define NK 10

typedef __attribute__((address_space(3))) unsigned int lds_u32;
typedef __attribute__((address_space(1))) const unsigned int gbl_u32;

__device__ __forceinline__ void gload_lds16(const void* g, void* l) {
  __builtin_amdgcn_global_load_lds((gbl_u32*)(uintptr_t)g, (lds_u32*)(uintptr_t)l, 16, 0, 0);
}

// ---------------- prep kernels ----------------

__global__ void split_kernel(const float* __restrict__ src, f16* __restrict__ hi,
                             f16* __restrict__ lo, int n) {
  int i = blockIdx.x * 256 + threadIdx.x;
  int stride = gridDim.x * 256;
  for (; i < n; i += stride) {
    float v = src[i];
    f16 h = (f16)v;
    hi[i] = h;
    lo[i] = (f16)(v - (float)h);
  }
}

__global__ void splith_kernel(const float* __restrict__ src, f16* __restrict__ hi, int n) {
  int i = blockIdx.x * 256 + threadIdx.x;
  int stride = gridDim.x * 256;
  for (; i < n; i += stride) hi[i] = (f16)src[i];
}

__global__ void emean_kernel(const float* __restrict__ E, float* __restrict__ Emean) {
  int i = blockIdx.x * 256 + threadIdx.x;
  if (i < NK * DIM) {
    float s = 0.f;
#pragma unroll
    for (int p = 0; p < NP; ++p) s += E[p * NK * DIM + i];
    Emean[i] = s * 0.125f;
  }
}

__global__ void enorm_kernel(const float* __restrict__ E, const float* __restrict__ Emean,
                             float* __restrict__ E2, float* __restrict__ E2m) {
  int bid = blockIdx.x;  // 0..79 -> E2[p*10+k]; 80..89 -> E2m[k]
  const float* src = (bid < 80) ? (E + (size_t)bid * DIM) : (Emean + (size_t)(bid - 80) * DIM);
  int lane = threadIdx.x;  // block = 64
  float s = 0.f;
  for (int i = lane; i < DIM; i += 64) {
    float v = src[i];
    s = fmaf(v, v, s);
  }
#pragma unroll
  for (int m = 1; m < 64; m <<= 1) s += __shfl_xor(s, m, 64);
  if (lane == 0) {
    if (bid < 80) E2[bid] = s;
    else E2m[bid - 80] = s;
  }
}

// Et[p][k][h] = sum_d W2[p][d][h]*E[p][k][d];  c[p][k] = b2[p]·E[p][k]
__global__ __launch_bounds__(512) void etilde_kernel(const float* __restrict__ W2,
                                                     const float* __restrict__ b2,
                                                     const float* __restrict__ E,
                                                     float* __restrict__ Et,
                                                     float* __restrict__ c_) {
  const int p = blockIdx.x / NK, k = blockIdx.x % NK;
  const int h = threadIdx.x;  // 512 threads
  __shared__ float Er[512];
  __shared__ float red[8];
  Er[h] = E[((size_t)p * NK + k) * DIM + h];
  __syncthreads();
  const float* Wp = W2 + (size_t)p * DIM * DIM;
  float s = 0.f;
#pragma unroll 8
  for (int d = 0; d < DIM; ++d) s = fmaf(Wp[(size_t)d * DIM + h], Er[d], s);
  Et[((size_t)p * NK + k) * DIM + h] = s;
  float t = b2[p * DIM + h] * Er[h];
#pragma unroll
  for (int m = 1; m < 64; m <<= 1) t += __shfl_xor(t, m, 64);
  if ((h & 63) == 0) red[h >> 6] = t;
  __syncthreads();
  if (h == 0) {
    float cc = 0.f;
#pragma unroll
    for (int i = 0; i < 8; ++i) cc += red[i];
    c_[p * NK + k] = cc;
  }
}

// ---------------- m97-style 128x128 GEMM-BT ----------------
// C[m][n] = sum_k A[m][k]*B[n][k].
// NPROD=3: split-fp16 (Ah·Bh, Ah·Bl, Al·Bh k-major). NPROD=1: Ah·Bh only.
// GRP: L2 banding — XCD chunk walks GRP-bm bands bm-fastest.
// EPI 0 (GEMM1): h=relu(acc+bias) -> Oh (coalesced via LDS) + fused fp32
//                g-partials: gpart[p][ch][row][12], ch = (bn&3)*2+wc.
// EPI 1 (GEMM2): row partials of sum(z^2) -> part2[p][ch][row], ch = bn*2+wc.

template <int EPI, int NBN, int NPROD, int GRP>
__global__ __launch_bounds__(256) void gemmA(
    const f16* __restrict__ Ah_, const f16* __restrict__ Al_, int lda, int apitch,
    const f16* __restrict__ Bh_, const f16* __restrict__ Bl_, int bpitch,
    const float* __restrict__ bias_, int bias_pitch,
    f16* __restrict__ Oh, int ldo,
    float* __restrict__ part2, const float* __restrict__ Et_, float* __restrict__ gpart) {
  __shared__ f16 smem[32768];  // 64 KB: 2 buf x [A 8192 | B 8192]
  const int tid = threadIdx.x;
  const int lane = tid & 63;
  const int wave = tid >> 6;
  const int wr = wave >> 1, wc = wave & 1;
  const int p = blockIdx.z;

  const int q8 = gridDim.x >> 3;
  const int bid = blockIdx.x;
  const int swz = (bid & 7) * q8 + (bid >> 3);
  const int band = swz / (GRP * NBN);
  const int r_ = swz % (GRP * NBN);
  const int bm = band * GRP + (r_ % GRP);
  const int bn = r_ / GRP;
  const int m0 = bm * 128, n0 = bn * 128;

  const f16* Ahp = Ah_ + (size_t)p * apitch;
  const f16* Alp = Al_ + (size_t)p * apitch;
  const f16* Bhp = Bh_ + (size_t)p * bpitch;
  const f16* Blp = Bl_ + (size_t)p * bpitch;

  const int NT = (NPROD == 3) ? 24 : 8;

  f32x4 acc[4][4] = {};

  auto stage = [&](int buf, int t) {
    const f16* As;
    const f16* Bs;
    int k0;
    if (NPROD == 3) {
      int pr = t % 3;  // 0:(Ah,Bh) 1:(Ah,Bl) 2:(Al,Bh)
      As = (pr == 2) ? Alp : Ahp;
      Bs = (pr == 1) ? Blp : Bhp;
      k0 = (t / 3) * 64;
    } else {
      As = Ahp;
      Bs = Bhp;
      k0 = t * 64;
    }
    f16* sA = smem + buf * 16384;
    f16* sB = sA + 8192;
#pragma unroll
    for (int j = 0; j < 4; ++j) {
      int r = j * 32 + (tid >> 3);
      int c = ((tid & 7) ^ (r & 7)) * 8;  // pre-swizzled source col
      gload_lds16(As + (size_t)(m0 + r) * lda + k0 + c, sA + j * 2048 + tid * 8);
      gload_lds16(Bs + (size_t)(n0 + r) * 512 + k0 + c, sB + j * 2048 + tid * 8);
    }
  };

  stage(0, 0);
  __syncthreads();

  const int g = lane >> 4, rl = lane & 15;

  for (int s = 0; s < NT; ++s) {
    int nx = s + 1;
    if (nx < NT) stage(nx & 1, nx);
    const char* sA = (const char*)(smem + (s & 1) * 16384);
    const char* sB = sA + 16384;  // bytes
    f16x8 af[4][2], bf[4][2];
#pragma unroll
    for (int i = 0; i < 4; ++i) {
      int ra = wr * 64 + i * 16 + rl;
      int rb = wc * 64 + i * 16 + rl;
#pragma unroll
      for (int kk = 0; kk < 2; ++kk) {
        int cb = kk * 64 + g * 16;
        af[i][kk] = *(const f16x8*)(sA + ra * 128 + (cb ^ ((ra & 7) << 4)));
        bf[i][kk] = *(const f16x8*)(sB + rb * 128 + (cb ^ ((rb & 7) << 4)));
      }
    }
#pragma unroll
    for (int i = 0; i < 4; ++i)
#pragma unroll
      for (int jn = 0; jn < 4; ++jn)
#pragma unroll
        for (int kk = 0; kk < 2; ++kk)
          acc[i][jn] = __builtin_amdgcn_mfma_f32_16x16x32_f16(af[i][kk], bf[jn][kk], acc[i][jn], 0, 0, 0);
    __syncthreads();
  }

  if (EPI == 0) {
    // GEMM1 epilogue: h = relu(z), stage Oh in LDS for coalesced writes,
    // fused fp32 g-partials vs Et.
    const int pp = bn >> 2, cc = bn & 3;
    float bv[4];
#pragma unroll
    for (int jn = 0; jn < 4; ++jn) bv[jn] = bias_[n0 + wc * 64 + jn * 16 + rl];
    float ev[NK][4];
#pragma unroll
    for (int jn = 0; jn < 4; ++jn) {
      int col = cc * 128 + wc * 64 + jn * 16 + rl;
      const float* ep = Et_ + (size_t)pp * NK * DIM + col;
#pragma unroll
      for (int k = 0; k < NK; ++k) ev[k][jn] = ep[k * DIM];
    }
    f16* sOut = smem;  // 32 KB [128][128] f16
    float* pgb = gpart + (size_t)(pp * 8 + cc * 2 + wc) * B_ROWS * 12;
#pragma unroll
    for (int i = 0; i < 4; ++i) {
#pragma unroll
      for (int r = 0; r < 4; ++r) {
        int row = wr * 64 + i * 16 + g * 4 + r;  // local row
        float qv[NK];
#pragma unroll
        for (int k = 0; k < NK; ++k) qv[k] = 0.f;
#pragma unroll
        for (int jn = 0; jn < 4; ++jn) {
          float z = fmaxf(acc[i][jn][r] + bv[jn], 0.f);
          sOut[row * 128 + wc * 64 + jn * 16 + rl] = (f16)z;
#pragma unroll
          for (int k = 0; k < NK; ++k) qv[k] = fmaf(z, ev[k][jn], qv[k]);
        }
#pragma unroll
        for (int m = 1; m < 16; m <<= 1)
#pragma unroll
          for (int k = 0; k < NK; ++k) qv[k] += __shfl_xor(qv[k], m, 64);
        if (rl == 0) {
          float* o = pgb + (size_t)(m0 + row) * 12;
          *(float4*)o = make_float4(qv[0], qv[1], qv[2], qv[3]);
          *(float4*)(o + 4) = make_float4(qv[4], qv[5], qv[6], qv[7]);
          *(float2*)(o + 8) = make_float2(qv[8], qv[9]);
        }
      }
    }
    __syncthreads();
#pragma unroll
    for (int j = 0; j < 8; ++j) {
      int row = j * 16 + (tid >> 4);
      f16x8 vv = *(const f16x8*)(sOut + row * 128 + (tid & 15) * 8);
      *(f16x8*)(Oh + (size_t)(m0 + row) * ldo + n0 + (tid & 15) * 8) = vv;
    }
  } else {
    const float* bp = bias_ + (size_t)p * bias_pitch;
    float bvals[4];
#pragma unroll
    for (int jn = 0; jn < 4; ++jn) bvals[jn] = bp[n0 + wc * 64 + jn * 16 + rl];
    const int ch = bn * 2 + wc;  // 0..7 (NBN=4)
    float* pb = part2 + (size_t)(p * 8 + ch) * B_ROWS;
#pragma unroll
    for (int i = 0; i < 4; ++i) {
#pragma unroll
      for (int r = 0; r < 4; ++r) {
        float q = 0.f;
#pragma unroll
        for (int jn = 0; jn < 4; ++jn) {
          float z = acc[i][jn][r] + bvals[jn];
          q = fmaf(z, z, q);
        }
#pragma unroll
        for (int m = 1; m < 16; m <<= 1) q += __shfl_xor(q, m, 64);
        if (rl == 0) pb[m0 + wr * 64 + i * 16 + g * 4 + r] = q;
      }
    }
  }
}

// ---------------- final: reduce g-partials, assemble dist, argmin, outputs ----------------

__global__ __launch_bounds__(256) void final_kernel(
    const float* __restrict__ X, const float* __restrict__ part2,
    const float* __restrict__ gpart, const float* __restrict__ c_,
    const float* __restrict__ E2, const float* __restrict__ Emean,
    const float* __restrict__ E2m, const int* __restrict__ label,
    float* __restrict__ vq_z, float* __restrict__ dist,
    float* __restrict__ loss, float* __restrict__ changed) {
  __shared__ float Em[NK * DIM];
  __shared__ float e2s[NK];
  for (int i = threadIdx.x; i < NK * DIM; i += 256) Em[i] = Emean[i];
  if (threadIdx.x < NK) e2s[threadIdx.x] = E2m[threadIdx.x];
  __syncthreads();
  const int lane = threadIdx.x & 63, wave = threadIdx.x >> 6;
  const int pl = lane & 7, kh = lane >> 3;
  for (int rr = 0; rr < 4; ++rr) {
    int b = blockIdx.x * 16 + wave * 4 + rr;
    // zsq[pl] broadcast to all lanes of the p-group
    float zq = part2[(size_t)(pl * 8 + kh) * B_ROWS + b];
    zq += __shfl_xor(zq, 8, 64);
    zq += __shfl_xor(zq, 16, 64);
    zq += __shfl_xor(zq, 32, 64);
    // g sums over 8 chunks
    size_t gb = ((size_t)(pl * 8) * B_ROWS + b) * 12;
    float g0 = 0.f, g1 = 0.f;
#pragma unroll
    for (int ch = 0; ch < 8; ++ch) {
      const float* q = gpart + gb + (size_t)ch * B_ROWS * 12;
      g0 += q[kh];
      if (lane < 16) g1 += q[8 + kh];
    }
    float dv0 = zq + E2[pl * NK + kh] - 2.f * (g0 + c_[pl * NK + kh]);
    float dv1 = (lane < 16) ? zq + E2[pl * NK + 8 + kh] - 2.f * (g1 + c_[pl * NK + 8 + kh]) : 0.f;
    dist[((size_t)pl * B_ROWS + b) * NK + kh] = dv0;
    if (lane < 16) dist[((size_t)pl * B_ROWS + b) * NK + 8 + kh] = dv1;
    // mean over p (sum; xor over low 3 lane bits)
    float v0 = dv0, v1 = dv1;
#pragma unroll
    for (int m = 1; m < 8; m <<= 1) {
      v0 += __shfl_xor(v0, m, 64);
      v1 += __shfl_xor(v1, m, 64);
    }
    float a[NK];
#pragma unroll
    for (int k = 0; k < 8; ++k) a[k] = __shfl(v0, k * 8, 64);
    a[8] = __shfl(v1, 0, 64);
    a[9] = __shfl(v1, 8, 64);
    int idx = 0;
    float mn = a[0];
#pragma unroll
    for (int k = 1; k < NK; ++k) {
      if (a[k] < mn) { mn = a[k]; idx = k; }
    }
    // x-dependent loss terms
    const float* xr = X + (size_t)b * DIM;
    float sx = 0.f, dx[NK] = {};
#pragma unroll
    for (int j = 0; j < 8; ++j) {
      float x = xr[j * 64 + lane];
      sx = fmaf(x, x, sx);
#pragma unroll
      for (int k = 0; k < NK; ++k) dx[k] = fmaf(x, Em[k * DIM + j * 64 + lane], dx[k]);
    }
#pragma unroll
    for (int m = 1; m < 64; m <<= 1) {
      sx += __shfl_xor(sx, m, 64);
#pragma unroll
      for (int k = 0; k < NK; ++k) dx[k] += __shfl_xor(dx[k], m, 64);
    }
    if (lane == 0) {
#pragma unroll
      for (int k = 0; k < NK; ++k)
        loss[(size_t)k * B_ROWS + b] = 1.25f * (sx - 2.f * dx[k] + e2s[k]);
    }
    int lab = label[b];
#pragma unroll
    for (int j = 0; j < 8; ++j) {
      int c = j * 64 + lane;
      vq_z[(size_t)b * DIM + c] = Em[idx * DIM + c];
      changed[(size_t)b * DIM + c] = Em[lab * DIM + c];
    }
  }
}

// ---------------- all_vq_z broadcast ----------------

__global__ void bcast_kernel(const float* __restrict__ Emean, float4* __restrict__ out) {
  const float4* Em4 = (const float4*)Emean;
  size_t n = (size_t)NK * B_ROWS * (DIM / 4);
  for (size_t i = (size_t)blockIdx.x * blockDim.x + threadIdx.x; i < n;
       i += (size_t)gridDim.x * blockDim.x) {
    size_t kb = i >> 7;
    int d4 = (int)(i & 127);
    int k = (int)(kb >> 15);
    out[i] = Em4[k * 128 + d4];
  }
}

// ---------------- launch ----------------

extern "C" void kernel_launch(void* const* d_in, const int* in_sizes, int n_in,
                              void* d_out, int out_size, void* d_ws, size_t ws_size,
                              hipStream_t stream) {
  const float* X = (const float*)d_in[0];
  const float* W1 = (const float*)d_in[1];
  const float* b1 = (const float*)d_in[2];
  const float* W2 = (const float*)d_in[3];
  const float* b2 = (const float*)d_in[4];
  const float* E = (const float*)d_in[5];
  const int* lab = (const int*)d_in[6];
  float* out = (float*)d_out;

  // output layout (flat f32, return order)
  float* vq_z = out;                               // 16,777,216
  float* dist = out + 16777216;                    // 2,621,440
  float* avz = out + 16777216 + 2621440;           // 167,772,160
  float* loss = avz + 167772160;                   // 327,680
  float* chg = loss + 327680;                      // 16,777,216

  // scratch carved from output regions (consumed before final/bcast writes):
  f16* Xh = (f16*)vq_z;                       // 33.5 MB
  f16* Xl = Xh + 16777216;                    // fills vq_z region
  f16* Hh = (f16*)avz;                        // stacked H [32768][4096] f16 = 268 MB
  float* part2 = avz + 67108864;              // [8][8][32768] f32 = 8 MB
  float* gpart = part2 + 2097152;             // [8][8][32768][12] f32 = 100 MB

  // small ws allocations (~13 MB)
  char* w = (char*)d_ws;
  f16* W1h = (f16*)w; w += 4194304;
  f16* W1l = (f16*)w; w += 4194304;
  f16* W2h = (f16*)w; w += 4194304;
  float* Emean = (float*)w; w += NK * DIM * 4;
  float* E2 = (float*)w; w += 512;
  float* E2m = (float*)w; w += 256;
  float* Et = (float*)w; w += NP * NK * DIM * 4;  // 164 KB
  float* c_ = (float*)w; w += 512;

  split_kernel<<<2048, 256, 0, stream>>>(X, Xh, Xl, 16777216);
  split_kernel<<<512, 256, 0, stream>>>(W1, W1h, W1l, 2097152);
  splith_kernel<<<512, 256, 0, stream>>>(W2, W2h, 2097152);
  emean_kernel<<<20, 256, 0, stream>>>(E, Emean);
  enorm_kernel<<<90, 64, 0, stream>>>(E, Emean, E2, E2m);
  etilde_kernel<<<80, 512, 0, stream>>>(W2, b2, E, Et, c_);

  // GEMM1: [32768x512] x [4096x512]^T -> Hh (relu) + fused g-partials
  gemmA<0, 32, 3, 8><<<dim3(8192, 1, 1), 256, 0, stream>>>(
      Xh, Xl, 512, 0, W1h, W1l, 0, b1, 0, Hh, 4096, nullptr, Et, gpart);
  // GEMM2: per-p [32768x512] x [512x512]^T, 1 product (Hh*W2h) -> zsq partials
  gemmA<1, 4, 1, 1><<<dim3(1024, 1, NP), 256, 0, stream>>>(
      Hh, Hh, 4096, 512, W2h, W2h, 262144, b2, 512, nullptr, 0, part2, nullptr, nullptr);

  final_kernel<<<2048, 256, 0, stream>>>(X, part2, gpart, c_, E2, Emean, E2m, lab,
                                         vq_z, dist, loss, chg);
  bcast_kernel<<<4096, 256, 0, stream>>>(Emean, (float4*)avz);
}